// Round 9
// baseline (257.584 us; speedup 1.0000x reference)
//
#include <hip/hip_runtime.h>
#include <hip/hip_fp16.h>

// MHA with softmax over HEADS axis. R9: revert R8 (z=4 ctx, 128x64 GEMMs,
// 64x64 denom) + DEPTH-2 software pipeline everywhere: triple-buffered LDS,
// prologue issues periods 0 and 1, period t waits vmcnt(own 4|3 ops), issues
// t+2, computes t -> every DMA gets ~2 compute phases (~900cyc HBM latency).

typedef _Float16 f16;
typedef _Float16 f16x4 __attribute__((ext_vector_type(4)));
typedef _Float16 f16x8 __attribute__((ext_vector_type(8)));
typedef float    f32x4 __attribute__((ext_vector_type(4)));

#define S_LEN 2048
#define DIM   1024
#define NH    16
#define DK    64
// exp(s * 0.125) = exp2(s * log2(e)/8)
#define EXP2K 0.1803368801111244f

#define MFMA(a, b, c) __builtin_amdgcn_mfma_f32_16x16x32_f16(a, b, c, 0, 0, 0)

#define VM_WAIT0   asm volatile("s_waitcnt vmcnt(0)" ::: "memory")
#define VM_WAIT3   asm volatile("s_waitcnt vmcnt(3)" ::: "memory")
#define VM_WAIT4   asm volatile("s_waitcnt vmcnt(4)" ::: "memory")
#define WG_BARRIER asm volatile("s_barrier" ::: "memory")

typedef __attribute__((address_space(1))) void g_void;
typedef __attribute__((address_space(3))) void l_void;

static __device__ __forceinline__ void gload_lds16(const void* g, void* l) {
  __builtin_amdgcn_global_load_lds((g_void*)g, (l_void*)l, 16, 0, 0);
}

static __device__ __forceinline__ float exp_s(float s) {
  return __builtin_amdgcn_exp2f(s * EXP2K);  // identical in denom & ctx
}

// ---------------------------------------------------------------- merged cvt fp32->f16
__global__ __launch_bounds__(256) void cvt_all(
    const float* __restrict__ q, const float* __restrict__ k, const float* __restrict__ v,
    const float* __restrict__ Wq, const float* __restrict__ Wk, const float* __restrict__ Wv,
    const float* __restrict__ Wo, f16* __restrict__ qh, f16* __restrict__ kh,
    f16* __restrict__ vh, f16* __restrict__ wqh, f16* __restrict__ wkh,
    f16* __restrict__ wvh, f16* __restrict__ woh) {
  const size_t M = 1048576;
  const int seg = blockIdx.y;
  const float* src;
  f16* dst;
  switch (seg) {
    case 0: src = q;      dst = qh;      break;
    case 1: src = q + M;  dst = qh + M;  break;
    case 2: src = k;      dst = kh;      break;
    case 3: src = k + M;  dst = kh + M;  break;
    case 4: src = v;      dst = vh;      break;
    case 5: src = v + M;  dst = vh + M;  break;
    case 6: src = Wq;     dst = wqh;     break;
    case 7: src = Wk;     dst = wkh;     break;
    case 8: src = Wv;     dst = wvh;     break;
    default: src = Wo;    dst = woh;     break;
  }
  int i = blockIdx.x * 256 + threadIdx.x;
  float4 vv = ((const float4*)src)[i];
  f16x4 o = {(f16)vv.x, (f16)vv.y, (f16)vv.z, (f16)vv.w};
  ((f16x4*)dst)[i] = o;
}

__global__ __launch_bounds__(256) void cvt_f32_f16(const float* __restrict__ src,
                                                   f16* __restrict__ dst, int n4) {
  int i = blockIdx.x * 256 + threadIdx.x;
  if (i < n4) {
    float4 v = ((const float4*)src)[i];
    f16x4 o = {(f16)v.x, (f16)v.y, (f16)v.z, (f16)v.w};
    ((f16x4*)dst)[i] = o;
  }
}

// ---------------------------------------------------------------- depth-2 128x64 GEMM core
// BK=32, triple-buffered (36KB LDS). 3 DMA + 8 MFMA per wave-period.
static __device__ __forceinline__ void gemm32_core(const f16* __restrict__ X,
                                                   const f16* __restrict__ W,
                                                   int k0, int k1, int bm, int bn,
                                                   f16* As, f16* Bs,
                                                   f32x4 (&acc)[4][2]) {
  const int tid = threadIdx.x;
  const int wv = tid >> 6;
  const int lane = tid & 63;
  const int qd = lane >> 4;
  const int l16 = lane & 15;
  const int wm = (wv & 1) * 64;
  const int wn = (wv >> 1) * 32;
  const int lr4 = lane >> 2, lc4 = lane & 3;

  const f16* gA = X + (size_t)(bm + wv * 32 + lr4) * DIM + k0 + lc4 * 8;
  const f16* gB = W + (size_t)(bn + wv * 16 + lr4) * DIM + k0 + lc4 * 8;
  const int np = (k1 - k0) >> 5;

  // prologue: periods 0,1 into bufs 0,1
#pragma unroll
  for (int p = 0; p < 2; p++) {
    gload_lds16(gA + p * 32, As + p * (128 * 32) + (wv * 32) * 32);
    gload_lds16(gA + p * 32 + 16 * DIM, As + p * (128 * 32) + (wv * 32 + 16) * 32);
    gload_lds16(gB + p * 32, Bs + p * (64 * 32) + (wv * 16) * 32);
  }

  int b0 = 0;
  for (int t = 0; t < np; t++) {
    if (t == np - 1) { VM_WAIT0; } else { VM_WAIT3; }
    WG_BARRIER;
    if (t + 2 < np) {
      int b2 = b0 + 2; if (b2 >= 3) b2 -= 3;
      const f16* gA2 = gA + (t + 2) * 32;
      gload_lds16(gA2, As + b2 * (128 * 32) + (wv * 32) * 32);
      gload_lds16(gA2 + 16 * DIM, As + b2 * (128 * 32) + (wv * 32 + 16) * 32);
      gload_lds16(gB + (t + 2) * 32, Bs + b2 * (64 * 32) + (wv * 16) * 32);
    }
    const f16* A = As + b0 * (128 * 32);
    const f16* B = Bs + b0 * (64 * 32);
    f16x8 bf[2];
#pragma unroll
    for (int ni = 0; ni < 2; ni++)
      bf[ni] = *(const f16x8*)&B[(wn + ni * 16 + l16) * 32 + qd * 8];
#pragma unroll
    for (int mi = 0; mi < 4; mi++) {
      f16x8 af = *(const f16x8*)&A[(wm + mi * 16 + l16) * 32 + qd * 8];
#pragma unroll
      for (int ni = 0; ni < 2; ni++)
        acc[mi][ni] = MFMA(af, bf[ni], acc[mi][ni]);
    }
    b0 = (b0 == 2) ? 0 : b0 + 1;
  }
}

// ---------------------------------------------------------------- merged QKV proj
// grid (DIM/64, S/128, 3). z=0: Qp; z=1: Kp; z=2: Vt (transposed)
__global__ __launch_bounds__(256) void gemm_qkv(
    const f16* __restrict__ X0, const f16* __restrict__ X1, const f16* __restrict__ X2,
    const f16* __restrict__ W0, const f16* __restrict__ W1, const f16* __restrict__ W2,
    const float* __restrict__ b0, const float* __restrict__ b1, const float* __restrict__ b2,
    f16* __restrict__ o0, f16* __restrict__ o1, f16* __restrict__ o2) {
  __shared__ __align__(16) f16 As[3 * 128 * 32];
  __shared__ __align__(16) f16 Bs[3 * 64 * 32];
  const int z = blockIdx.z;
  const f16* X = z == 0 ? X0 : z == 1 ? X1 : X2;
  const f16* W = z == 0 ? W0 : z == 1 ? W1 : W2;
  const float* bias = z == 0 ? b0 : z == 1 ? b1 : b2;
  f16* outh = z == 0 ? o0 : z == 1 ? o1 : o2;

  const int bm = blockIdx.y * 128, bn = blockIdx.x * 64;
  f32x4 acc[4][2];
#pragma unroll
  for (int a = 0; a < 4; a++)
#pragma unroll
    for (int b = 0; b < 2; b++) acc[a][b] = (f32x4){0.f, 0.f, 0.f, 0.f};

  gemm32_core(X, W, 0, DIM, bm, bn, As, Bs, acc);

  const int tid = threadIdx.x;
  const int wv = tid >> 6, lane = tid & 63;
  const int qd = lane >> 4, l16 = lane & 15;
  const int wm = (wv & 1) * 64, wn = (wv >> 1) * 32;
#pragma unroll
  for (int mi = 0; mi < 4; mi++) {
#pragma unroll
    for (int ni = 0; ni < 2; ni++) {
      const int gm = bm + wm + mi * 16 + qd * 4;
      const int gn = bn + wn + ni * 16 + l16;
      const float bs = bias[gn];
      if (z == 2) {
        f16x4 o = {(f16)(acc[mi][ni][0] + bs), (f16)(acc[mi][ni][1] + bs),
                   (f16)(acc[mi][ni][2] + bs), (f16)(acc[mi][ni][3] + bs)};
        *(f16x4*)&outh[(size_t)gn * S_LEN + gm] = o;  // Vt[d][j]
      } else {
#pragma unroll
        for (int r = 0; r < 4; r++)
          outh[(size_t)(gm + r) * DIM + gn] = (f16)(acc[mi][ni][r] + bs);
      }
    }
  }
}

// ---------------------------------------------------------------- out GEMM 128x64, splitK2
__global__ __launch_bounds__(256) void gemm_out(const f16* __restrict__ X,
                                                const f16* __restrict__ W,
                                                const float* __restrict__ bias,
                                                float* __restrict__ outf) {
  __shared__ __align__(16) f16 As[3 * 128 * 32];
  __shared__ __align__(16) f16 Bs[3 * 64 * 32];
  const int z = blockIdx.z;
  const int bm = blockIdx.y * 128, bn = blockIdx.x * 64;
  f32x4 acc[4][2];
#pragma unroll
  for (int a = 0; a < 4; a++)
#pragma unroll
    for (int b = 0; b < 2; b++) acc[a][b] = (f32x4){0.f, 0.f, 0.f, 0.f};

  gemm32_core(X, W, z * (DIM / 2), (z + 1) * (DIM / 2), bm, bn, As, Bs, acc);

  const int tid = threadIdx.x;
  const int wv = tid >> 6, lane = tid & 63;
  const int qd = lane >> 4, l16 = lane & 15;
  const int wm = (wv & 1) * 64, wn = (wv >> 1) * 32;
#pragma unroll
  for (int mi = 0; mi < 4; mi++) {
#pragma unroll
    for (int ni = 0; ni < 2; ni++) {
      const int gm = bm + wm + mi * 16 + qd * 4;
      const int gn = bn + wn + ni * 16 + l16;
      const float bs = z == 0 ? bias[gn] : 0.f;
#pragma unroll
      for (int r = 0; r < 4; r++)
        atomicAdd(&outf[(size_t)(gm + r) * DIM + gn], acc[mi][ni][r] + bs);
    }
  }
}

// ---------------------------------------------------------------- pass A: IDn = 1/sum_h exp
// 64x64 tile, grid (32,32)=1024. Depth-2 pipeline over heads, triple buffer
// (48KB LDS -> 3 blocks/CU). 4 DMA + 8 MFMA + 16 exp per wave-period.
__global__ __launch_bounds__(256) void attn_denom(const f16* __restrict__ Qp,
                                                  const f16* __restrict__ Kp,
                                                  f16* __restrict__ IDn) {
  __shared__ __align__(16) f16 Qs[3][2][64 * 32];  // [buf][kk][row][32]
  __shared__ __align__(16) f16 Ks[3][2][64 * 32];
  const int tid = threadIdx.x;
  const int wv = tid >> 6;
  const int lane = tid & 63;
  const int qd = lane >> 4;
  const int l16 = lane & 15;
  const int wm = (wv & 1) * 32, wn = (wv >> 1) * 32;
  const int bi = blockIdx.y * 64, bj = blockIdx.x * 64;
  const int lr4 = lane >> 2, lc4 = lane & 3;
  const int kkw = wv & 1;
  const int q0 = (wv >> 1) * 2;

  f32x4 dsum[2][2];
#pragma unroll
  for (int a = 0; a < 2; a++)
#pragma unroll
    for (int b = 0; b < 2; b++) dsum[a][b] = (f32x4){0.f, 0.f, 0.f, 0.f};

  // prologue: heads 0,1 into bufs 0,1
#pragma unroll
  for (int p = 0; p < 2; p++) {
    const f16* gq = Qp + (size_t)(bi + q0 * 16 + lr4) * DIM + p * DK + kkw * 32 + lc4 * 8;
    const f16* gk = Kp + (size_t)(bj + q0 * 16 + lr4) * DIM + p * DK + kkw * 32 + lc4 * 8;
#pragma unroll
    for (int t = 0; t < 2; t++) {
      gload_lds16(gq + (size_t)t * 16 * DIM, &Qs[p][kkw][(q0 + t) * 16 * 32]);
      gload_lds16(gk + (size_t)t * 16 * DIM, &Ks[p][kkw][(q0 + t) * 16 * 32]);
    }
  }

  int b0 = 0;
  for (int h = 0; h < NH; h++) {
    if (h == NH - 1) { VM_WAIT0; } else { VM_WAIT4; }
    WG_BARRIER;
    if (h + 2 < NH) {
      int b2 = b0 + 2; if (b2 >= 3) b2 -= 3;
      const int hc = (h + 2) * DK;
      const f16* gq = Qp + (size_t)(bi + q0 * 16 + lr4) * DIM + hc + kkw * 32 + lc4 * 8;
      const f16* gk = Kp + (size_t)(bj + q0 * 16 + lr4) * DIM + hc + kkw * 32 + lc4 * 8;
#pragma unroll
      for (int t = 0; t < 2; t++) {
        gload_lds16(gq + (size_t)t * 16 * DIM, &Qs[b2][kkw][(q0 + t) * 16 * 32]);
        gload_lds16(gk + (size_t)t * 16 * DIM, &Ks[b2][kkw][(q0 + t) * 16 * 32]);
      }
    }

#pragma unroll
    for (int mi = 0; mi < 2; mi++) {
      f16x8 af0 = *(const f16x8*)&Qs[b0][0][(wm + mi * 16 + l16) * 32 + qd * 8];
      f16x8 af1 = *(const f16x8*)&Qs[b0][1][(wm + mi * 16 + l16) * 32 + qd * 8];
#pragma unroll
      for (int ni = 0; ni < 2; ni++) {
        f16x8 bf0 = *(const f16x8*)&Ks[b0][0][(wn + ni * 16 + l16) * 32 + qd * 8];
        f16x8 bf1 = *(const f16x8*)&Ks[b0][1][(wn + ni * 16 + l16) * 32 + qd * 8];
        f32x4 s = {0.f, 0.f, 0.f, 0.f};
        s = MFMA(af0, bf0, s);  // kk order identical to attn_ctx
        s = MFMA(af1, bf1, s);
#pragma unroll
        for (int r = 0; r < 4; r++) dsum[mi][ni][r] += exp_s(s[r]);
      }
    }
    b0 = (b0 == 2) ? 0 : b0 + 1;
  }
#pragma unroll
  for (int mi = 0; mi < 2; mi++)
#pragma unroll
    for (int ni = 0; ni < 2; ni++)
#pragma unroll
      for (int r = 0; r < 4; r++) {
        const int gi = bi + wm + mi * 16 + qd * 4 + r;
        const int gj = bj + wn + ni * 16 + l16;
        IDn[(size_t)gi * S_LEN + gj] = (f16)(1.f / dsum[mi][ni][r]);
      }
}

// ---------------------------------------------------------------- pass B: ctx
// grid (S/128, NH, 4). i-tile 128 (wave=32 rows), 16x 32-j periods, depth-2
// pipeline: triple-buffered K/V LDS + idn register prefetch (static buf via
// macro). LDS 34KB -> 4 blocks/CU.
#define CTX_PERIOD(T, B, NB)                                                              \
  {                                                                                       \
    if ((T) == 15) { VM_WAIT0; } else { VM_WAIT4; }                                       \
    WG_BARRIER;                                                                           \
    if ((T) + 2 < 16) {                                                                   \
      const int j2 = jb + ((T) + 2) * 32;                                                 \
      gload_lds16(Kp + (size_t)(j2 + rhw * 16 + lr4) * DIM + h * DK + kkw * 32 + lc4 * 8, \
                  &Ks[NB][kkw][(rhw * 16) * 32]);                                         \
      gload_lds16(Vt + (size_t)(h * DK + wv * 16 + lr4) * S_LEN + j2 + lc4 * 8,           \
                  &Vs[NB][(wv * 16) * 32]);                                               \
      idn[NB][0] = *(const f16x8*)(IDn + (size_t)(iw + l16) * S_LEN + j2 + qd * 8);       \
      idn[NB][1] = *(const f16x8*)(IDn + (size_t)(iw + 16 + l16) * S_LEN + j2 + qd * 8);  \
    }                                                                                     \
    f16x8 bk[2][2];                                                                       \
    _Pragma("unroll")                                                                     \
    for (int ni = 0; ni < 2; ni++)                                                        \
      _Pragma("unroll")                                                                   \
      for (int kk = 0; kk < 2; kk++)                                                      \
        bk[ni][kk] = *(const f16x8*)&Ks[B][kk][(ni * 16 + l16) * 32 + qd * 8];            \
    _Pragma("unroll")                                                                     \
    for (int mi = 0; mi < 2; mi++)                                                        \
      _Pragma("unroll")                                                                   \
      for (int ni = 0; ni < 2; ni++) {                                                    \
        f32x4 s = {0.f, 0.f, 0.f, 0.f};                                                   \
        s = MFMA(aq[mi][0], bk[ni][0], s);                                                \
        s = MFMA(aq[mi][1], bk[ni][1], s);                                                \
        _Pragma("unroll")                                                                 \
        for (int r = 0; r < 4; r++)                                                       \
          pl[(mi * 16 + qd * 4 + r) * 40 + ni * 16 + l16] = (f16)exp_s(s[r]);             \
      }                                                                                   \
    f16x8 bv[4];                                                                          \
    _Pragma("unroll")                                                                     \
    for (int nd = 0; nd < 4; nd++)                                                        \
      bv[nd] = *(const f16x8*)&Vs[B][(nd * 16 + l16) * 32 + qd * 8];                      \
    _Pragma("unroll")                                                                     \
    for (int mi = 0; mi < 2; mi++) {                                                      \
      f16x8 ef = *(const f16x8*)&pl[(mi * 16 + l16) * 40 + qd * 8];                       \
      f16x8 p = ef * idn[B][mi];                                                          \
      _Pragma("unroll")                                                                   \
      for (int nd = 0; nd < 4; nd++)                                                      \
        acc[mi][nd] = MFMA(p, bv[nd], acc[mi][nd]);                                       \
    }                                                                                     \
  }

__global__ __launch_bounds__(256, 4) void attn_ctx(const f16* __restrict__ Qp,
                                                   const f16* __restrict__ Kp,
                                                   const f16* __restrict__ Vt,
                                                   const f16* __restrict__ IDn,
                                                   float* __restrict__ Cp) {
  __shared__ __align__(16) f16 Ks[3][2][32 * 32];  // [buf][kk][j][32]
  __shared__ __align__(16) f16 Vs[3][64 * 32];     // [buf][d][j32]
  __shared__ __align__(16) f16 Pl[4][32 * 40];     // stride 40: 2-way only
  const int tid = threadIdx.x;
  const int wv = tid >> 6;
  const int lane = tid & 63;
  const int qd = lane >> 4;
  const int l16 = lane & 15;
  const int h = blockIdx.y;
  const int i0 = blockIdx.x * 128;
  const int iw = i0 + wv * 32;
  const int jb = blockIdx.z * 512;
  const int lr4 = lane >> 2, lc4 = lane & 3;
  const int kkw = wv & 1;
  const int rhw = wv >> 1;
  f16* pl = Pl[wv];

  f16x8 aq[2][2];
#pragma unroll
  for (int mi = 0; mi < 2; mi++)
#pragma unroll
    for (int kk = 0; kk < 2; kk++)
      aq[mi][kk] = *(const f16x8*)(Qp + (size_t)(iw + mi * 16 + l16) * DIM +
                                   h * DK + kk * 32 + qd * 8);

  f32x4 acc[2][4];
#pragma unroll
  for (int a = 0; a < 2; a++)
#pragma unroll
    for (int b = 0; b < 4; b++) acc[a][b] = (f32x4){0.f, 0.f, 0.f, 0.f};

  f16x8 idn[3][2];

  // prologue: periods 0,1 into bufs 0,1
#pragma unroll
  for (int p = 0; p < 2; p++) {
    const int j0 = jb + p * 32;
    gload_lds16(Kp + (size_t)(j0 + rhw * 16 + lr4) * DIM + h * DK + kkw * 32 + lc4 * 8,
                &Ks[p][kkw][(rhw * 16) * 32]);
    gload_lds16(Vt + (size_t)(h * DK + wv * 16 + lr4) * S_LEN + j0 + lc4 * 8,
                &Vs[p][(wv * 16) * 32]);
    idn[p][0] = *(const f16x8*)(IDn + (size_t)(iw + l16) * S_LEN + j0 + qd * 8);
    idn[p][1] = *(const f16x8*)(IDn + (size_t)(iw + 16 + l16) * S_LEN + j0 + qd * 8);
  }

  for (int tt = 0; tt < 15; tt += 3) {
    CTX_PERIOD(tt, 0, 2);
    CTX_PERIOD(tt + 1, 1, 0);
    CTX_PERIOD(tt + 2, 2, 1);
  }
  CTX_PERIOD(15, 0, 0);

#pragma unroll
  for (int mi = 0; mi < 2; mi++)
#pragma unroll
    for (int nd = 0; nd < 4; nd++)
#pragma unroll
      for (int r = 0; r < 4; r++)
        atomicAdd(&Cp[(size_t)(iw + mi * 16 + qd * 4 + r) * DIM + h * DK + nd * 16 + l16],
                  acc[mi][nd][r]);
}

// ---------------------------------------------------------------- launcher
extern "C" void kernel_launch(void* const* d_in, const int* in_sizes, int n_in,
                              void* d_out, int out_size, void* d_ws, size_t ws_size,
                              hipStream_t stream) {
  const float* q  = (const float*)d_in[0];
  const float* k  = (const float*)d_in[1];
  const float* v  = (const float*)d_in[2];
  const float* Wq = (const float*)d_in[3];
  const float* bq = (const float*)d_in[4];
  const float* Wk = (const float*)d_in[5];
  const float* bk = (const float*)d_in[6];
  const float* Wv = (const float*)d_in[7];
  const float* bv = (const float*)d_in[8];
  const float* Wo = (const float*)d_in[9];
  const float* bo = (const float*)d_in[10];
  float* out = (float*)d_out;

  f16* w = (f16*)d_ws;
  f16* qh  = w;                          // 0..4MB
  f16* kh  = qh + (size_t)S_LEN * DIM;   // 4..8
  f16* vh  = kh + (size_t)S_LEN * DIM;   // 8..12
  f16* wqh = vh + (size_t)S_LEN * DIM;   // 12..14
  f16* wkh = wqh + (size_t)DIM * DIM;    // 14..16
  f16* wvh = wkh + (size_t)DIM * DIM;    // 16..18
  f16* woh = wvh + (size_t)DIM * DIM;    // 18..20
  f16* Qp  = woh + (size_t)DIM * DIM;    // 20..24
  f16* Kp  = Qp + (size_t)S_LEN * DIM;   // 24..28
  f16* Vt  = Kp + (size_t)S_LEN * DIM;   // 28..32
  f16* IDn = qh;                         // 0..8MB  [qh/kh dead after gemm_qkv]
  float* Cp = (float*)vh;                // 8..16MB [vh/wqh/wkh dead]
  f16* Ct  = qh;                         // 0..4MB  [IDn dead after attn_ctx]

  dim3 b256(256);
  cvt_all<<<dim3(1024, 10), b256, 0, stream>>>(q, k, v, Wq, Wk, Wv, Wo,
                                               qh, kh, vh, wqh, wkh, wvh, woh);

  gemm_qkv<<<dim3(DIM / 64, S_LEN / 128, 3), b256, 0, stream>>>(
      qh, kh, vh, wqh, wkh, wvh, bq, bk, bv, Qp, Kp, Vt);

  hipMemsetAsync(Cp, 0, (size_t)S_LEN * DIM * sizeof(float), stream);
  hipMemsetAsync(out, 0, (size_t)S_LEN * DIM * sizeof(float), stream);

  attn_denom<<<dim3(S_LEN / 64, S_LEN / 64), b256, 0, stream>>>(Qp, Kp, IDn);
  attn_ctx<<<dim3(S_LEN / 128, NH, 4), b256, 0, stream>>>(Qp, Kp, Vt, IDn, Cp);

  const int nqkv4 = S_LEN * DIM / 4;
  cvt_f32_f16<<<nqkv4 / 256, b256, 0, stream>>>(Cp, Ct, nqkv4);

  gemm_out<<<dim3(DIM / 64, S_LEN / 128, 2), b256, 0, stream>>>(Ct, woh, bo, out);
}

// Round 10
// 235.682 us; speedup vs baseline: 1.0929x; 1.0929x over previous
//
#include <hip/hip_runtime.h>
#include <hip/hip_fp16.h>

// MHA with softmax over HEADS axis. R10: revert to R7 cores (proven best:
// depth-1 pipeline, raw s_barrier + vmcnt(0), unroll 2) + dispatch-chain cuts:
// - out-zeroing folded into cvt_all (segs 10,11)
// - cvt(Cp->Ct) kernel eliminated: gemm_out reads fp32 Cp directly with
//   inline load->cvt->ds_write A-staging (B stays on the DMA path)
// 8 -> 6 dispatches.

typedef _Float16 f16;
typedef _Float16 f16x4 __attribute__((ext_vector_type(4)));
typedef _Float16 f16x8 __attribute__((ext_vector_type(8)));
typedef float    f32x4 __attribute__((ext_vector_type(4)));

#define S_LEN 2048
#define DIM   1024
#define NH    16
#define DK    64
// exp(s * 0.125) = exp2(s * log2(e)/8)
#define EXP2K 0.1803368801111244f

#define MFMA(a, b, c) __builtin_amdgcn_mfma_f32_16x16x32_f16(a, b, c, 0, 0, 0)

#define VM_WAIT0   asm volatile("s_waitcnt vmcnt(0)" ::: "memory")
#define LGKM_WAIT0 asm volatile("s_waitcnt lgkmcnt(0)" ::: "memory")
#define WG_BARRIER asm volatile("s_barrier" ::: "memory")

typedef __attribute__((address_space(1))) void g_void;
typedef __attribute__((address_space(3))) void l_void;

static __device__ __forceinline__ void gload_lds16(const void* g, void* l) {
  __builtin_amdgcn_global_load_lds((g_void*)g, (l_void*)l, 16, 0, 0);
}

static __device__ __forceinline__ float exp_s(float s) {
  return __builtin_amdgcn_exp2f(s * EXP2K);  // identical in denom & ctx
}

// ---------------------------------------------------------------- merged cvt + out-zero
// segs 0-9: fp32->f16 cvt of q,k,v (2 each) and Wq,Wk,Wv,Wo; segs 10,11: zero d_out.
__global__ __launch_bounds__(256) void cvt_all(
    const float* __restrict__ q, const float* __restrict__ k, const float* __restrict__ v,
    const float* __restrict__ Wq, const float* __restrict__ Wk, const float* __restrict__ Wv,
    const float* __restrict__ Wo, f16* __restrict__ qh, f16* __restrict__ kh,
    f16* __restrict__ vh, f16* __restrict__ wqh, f16* __restrict__ wkh,
    f16* __restrict__ wvh, f16* __restrict__ woh, float* __restrict__ outz) {
  const size_t M = 1048576;
  const int seg = blockIdx.y;
  int i = blockIdx.x * 256 + threadIdx.x;
  if (seg >= 10) {  // zero d_out
    float4 z4 = {0.f, 0.f, 0.f, 0.f};
    ((float4*)(outz + (seg - 10) * M))[i] = z4;
    return;
  }
  const float* src;
  f16* dst;
  switch (seg) {
    case 0: src = q;      dst = qh;      break;
    case 1: src = q + M;  dst = qh + M;  break;
    case 2: src = k;      dst = kh;      break;
    case 3: src = k + M;  dst = kh + M;  break;
    case 4: src = v;      dst = vh;      break;
    case 5: src = v + M;  dst = vh + M;  break;
    case 6: src = Wq;     dst = wqh;     break;
    case 7: src = Wk;     dst = wkh;     break;
    case 8: src = Wv;     dst = wvh;     break;
    default: src = Wo;    dst = woh;     break;
  }
  float4 vv = ((const float4*)src)[i];
  f16x4 o = {(f16)vv.x, (f16)vv.y, (f16)vv.z, (f16)vv.w};
  ((f16x4*)dst)[i] = o;
}

// ---------------------------------------------------------------- pipelined 128x64 GEMM core
// BK=32 double-buffered (R7). 3 DMA + 8 MFMA per wave-period.
static __device__ __forceinline__ void gemm32_core(const f16* __restrict__ X,
                                                   const f16* __restrict__ W,
                                                   int k0, int k1, int bm, int bn,
                                                   f16* As, f16* Bs,
                                                   f32x4 (&acc)[4][2]) {
  const int tid = threadIdx.x;
  const int wv = tid >> 6;
  const int lane = tid & 63;
  const int qd = lane >> 4;
  const int l16 = lane & 15;
  const int wm = (wv & 1) * 64;
  const int wn = (wv >> 1) * 32;
  const int lr4 = lane >> 2, lc4 = lane & 3;

  const f16* gA = X + (size_t)(bm + wv * 32 + lr4) * DIM + k0 + lc4 * 8;
  const f16* gB = W + (size_t)(bn + wv * 16 + lr4) * DIM + k0 + lc4 * 8;
  const int np = (k1 - k0) >> 5;

  gload_lds16(gA, As + (wv * 32) * 32);
  gload_lds16(gA + 16 * DIM, As + (wv * 32 + 16) * 32);
  gload_lds16(gB, Bs + (wv * 16) * 32);

#pragma unroll 2
  for (int t = 0; t < np; t++) {
    const int buf = t & 1;
    VM_WAIT0;
    WG_BARRIER;
    if (t + 1 < np) {
      const f16* gA1 = gA + (t + 1) * 32;
      const f16* gB1 = gB + (t + 1) * 32;
      f16* dA = As + (buf ^ 1) * (128 * 32);
      f16* dB = Bs + (buf ^ 1) * (64 * 32);
      gload_lds16(gA1, dA + (wv * 32) * 32);
      gload_lds16(gA1 + 16 * DIM, dA + (wv * 32 + 16) * 32);
      gload_lds16(gB1, dB + (wv * 16) * 32);
    }
    const f16* A = As + buf * (128 * 32);
    const f16* B = Bs + buf * (64 * 32);
    f16x8 bf[2];
#pragma unroll
    for (int ni = 0; ni < 2; ni++)
      bf[ni] = *(const f16x8*)&B[(wn + ni * 16 + l16) * 32 + qd * 8];
#pragma unroll
    for (int mi = 0; mi < 4; mi++) {
      f16x8 af = *(const f16x8*)&A[(wm + mi * 16 + l16) * 32 + qd * 8];
#pragma unroll
      for (int ni = 0; ni < 2; ni++)
        acc[mi][ni] = MFMA(af, bf[ni], acc[mi][ni]);
    }
  }
}

// ---------------------------------------------------------------- merged QKV proj
__global__ __launch_bounds__(256) void gemm_qkv(
    const f16* __restrict__ X0, const f16* __restrict__ X1, const f16* __restrict__ X2,
    const f16* __restrict__ W0, const f16* __restrict__ W1, const f16* __restrict__ W2,
    const float* __restrict__ b0, const float* __restrict__ b1, const float* __restrict__ b2,
    f16* __restrict__ o0, f16* __restrict__ o1, f16* __restrict__ o2) {
  __shared__ __align__(16) f16 As[2 * 128 * 32];
  __shared__ __align__(16) f16 Bs[2 * 64 * 32];
  const int z = blockIdx.z;
  const f16* X = z == 0 ? X0 : z == 1 ? X1 : X2;
  const f16* W = z == 0 ? W0 : z == 1 ? W1 : W2;
  const float* bias = z == 0 ? b0 : z == 1 ? b1 : b2;
  f16* outh = z == 0 ? o0 : z == 1 ? o1 : o2;

  const int bm = blockIdx.y * 128, bn = blockIdx.x * 64;
  f32x4 acc[4][2];
#pragma unroll
  for (int a = 0; a < 4; a++)
#pragma unroll
    for (int b = 0; b < 2; b++) acc[a][b] = (f32x4){0.f, 0.f, 0.f, 0.f};

  gemm32_core(X, W, 0, DIM, bm, bn, As, Bs, acc);

  const int tid = threadIdx.x;
  const int wv = tid >> 6, lane = tid & 63;
  const int qd = lane >> 4, l16 = lane & 15;
  const int wm = (wv & 1) * 64, wn = (wv >> 1) * 32;
#pragma unroll
  for (int mi = 0; mi < 4; mi++) {
#pragma unroll
    for (int ni = 0; ni < 2; ni++) {
      const int gm = bm + wm + mi * 16 + qd * 4;
      const int gn = bn + wn + ni * 16 + l16;
      const float bs = bias[gn];
      if (z == 2) {
        f16x4 o = {(f16)(acc[mi][ni][0] + bs), (f16)(acc[mi][ni][1] + bs),
                   (f16)(acc[mi][ni][2] + bs), (f16)(acc[mi][ni][3] + bs)};
        *(f16x4*)&outh[(size_t)gn * S_LEN + gm] = o;  // Vt[d][j]
      } else {
#pragma unroll
        for (int r = 0; r < 4; r++)
          outh[(size_t)(gm + r) * DIM + gn] = (f16)(acc[mi][ni][r] + bs);
      }
    }
  }
}

// ---------------------------------------------------------------- out GEMM from fp32 Cp
// 128x64 tiles, splitK2, grid (DIM/64, S/128, 2). A staged inline: 4x float4
// load -> cvt f16 -> 2x ds_write_b128 per lane; B via DMA. Same pipeline
// discipline (double buffer, prefetch-before-compute).
__global__ __launch_bounds__(256) void gemm_out(const float* __restrict__ Xf,
                                                const f16* __restrict__ W,
                                                const float* __restrict__ bias,
                                                float* __restrict__ outf) {
  __shared__ __align__(16) f16 As[2][128 * 32];
  __shared__ __align__(16) f16 Bs[2][64 * 32];
  const int z = blockIdx.z;
  const int bm = blockIdx.y * 128, bn = blockIdx.x * 64;
  const int tid = threadIdx.x;
  const int wv = tid >> 6, lane = tid & 63;
  const int qd = lane >> 4, l16 = lane & 15;
  const int wm = (wv & 1) * 64, wn = (wv >> 1) * 32;
  const int lr4 = lane >> 2, lc4 = lane & 3;
  const int k0 = z * (DIM / 2);

  // A staging: lane covers row = wv*32 + (lane>>1), cols acol..acol+15 (fp32)
  const int arow = wv * 32 + (lane >> 1);
  const int acol = (lane & 1) * 16;
  const float* gA = Xf + (size_t)(bm + arow) * DIM + k0 + acol;
  const f16* gB = W + (size_t)(bn + wv * 16 + lr4) * DIM + k0 + lc4 * 8;

  f32x4 acc[4][2];
#pragma unroll
  for (int a = 0; a < 4; a++)
#pragma unroll
    for (int b = 0; b < 2; b++) acc[a][b] = (f32x4){0.f, 0.f, 0.f, 0.f};

  float4 ar[2][4];
  const int np = (DIM / 2) / 32;  // 16

  // prologue: period 0
#pragma unroll
  for (int j = 0; j < 4; j++) ar[0][j] = ((const float4*)gA)[j];
  gload_lds16(gB, &Bs[0][(wv * 16) * 32]);

#pragma unroll 2
  for (int t = 0; t < np; t++) {
    const int buf = t & 1;
    VM_WAIT0;  // ar[buf] loads + B-DMA(t) complete
    // cvt + write own A slice (cross-wave visible after the barrier)
    f16* aw = &As[buf][arow * 32 + acol];
#pragma unroll
    for (int j = 0; j < 2; j++) {
      float4 u = ar[buf][2 * j], v = ar[buf][2 * j + 1];
      f16x8 o = {(f16)u.x, (f16)u.y, (f16)u.z, (f16)u.w,
                 (f16)v.x, (f16)v.y, (f16)v.z, (f16)v.w};
      *(f16x8*)(aw + j * 8) = o;
    }
    LGKM_WAIT0;
    WG_BARRIER;  // all waves' A writes + B tiles for period t visible
    if (t + 1 < np) {
      const float* gA1 = gA + (t + 1) * 32;
#pragma unroll
      for (int j = 0; j < 4; j++) ar[buf ^ 1][j] = ((const float4*)gA1)[j];
      gload_lds16(gB + (t + 1) * 32, &Bs[buf ^ 1][(wv * 16) * 32]);
    }
    f16x8 bf[2];
#pragma unroll
    for (int ni = 0; ni < 2; ni++)
      bf[ni] = *(const f16x8*)&Bs[buf][(wn + ni * 16 + l16) * 32 + qd * 8];
#pragma unroll
    for (int mi = 0; mi < 4; mi++) {
      f16x8 af = *(const f16x8*)&As[buf][(wm + mi * 16 + l16) * 32 + qd * 8];
#pragma unroll
      for (int ni = 0; ni < 2; ni++)
        acc[mi][ni] = MFMA(af, bf[ni], acc[mi][ni]);
    }
  }

#pragma unroll
  for (int mi = 0; mi < 4; mi++) {
#pragma unroll
    for (int ni = 0; ni < 2; ni++) {
      const int gm = bm + wm + mi * 16 + qd * 4;
      const int gn = bn + wn + ni * 16 + l16;
      const float bs = z == 0 ? bias[gn] : 0.f;
#pragma unroll
      for (int r = 0; r < 4; r++)
        atomicAdd(&outf[(size_t)(gm + r) * DIM + gn], acc[mi][ni][r] + bs);
    }
  }
}

// ---------------------------------------------------------------- pass A: IDn = 1/sum_h exp
// R7 version: 64x64 tile, grid (32,32)=1024, double-buffer, unroll 2.
__global__ __launch_bounds__(256) void attn_denom(const f16* __restrict__ Qp,
                                                  const f16* __restrict__ Kp,
                                                  f16* __restrict__ IDn) {
  __shared__ __align__(16) f16 Qs[2][2][64 * 32];  // [buf][kk][row][32]
  __shared__ __align__(16) f16 Ks[2][2][64 * 32];
  const int tid = threadIdx.x;
  const int wv = tid >> 6;
  const int lane = tid & 63;
  const int qd = lane >> 4;
  const int l16 = lane & 15;
  const int wm = (wv & 1) * 32, wn = (wv >> 1) * 32;
  const int bi = blockIdx.y * 64, bj = blockIdx.x * 64;
  const int lr4 = lane >> 2, lc4 = lane & 3;
  const int kkw = wv & 1;
  const int q0 = (wv >> 1) * 2;

  f32x4 dsum[2][2];
#pragma unroll
  for (int a = 0; a < 2; a++)
#pragma unroll
    for (int b = 0; b < 2; b++) dsum[a][b] = (f32x4){0.f, 0.f, 0.f, 0.f};

  // prologue: head 0 -> buf 0
  {
    const f16* gq = Qp + (size_t)(bi + q0 * 16 + lr4) * DIM + kkw * 32 + lc4 * 8;
    const f16* gk = Kp + (size_t)(bj + q0 * 16 + lr4) * DIM + kkw * 32 + lc4 * 8;
#pragma unroll
    for (int t = 0; t < 2; t++) {
      gload_lds16(gq + (size_t)t * 16 * DIM, &Qs[0][kkw][(q0 + t) * 16 * 32]);
      gload_lds16(gk + (size_t)t * 16 * DIM, &Ks[0][kkw][(q0 + t) * 16 * 32]);
    }
  }

#pragma unroll 2
  for (int h = 0; h < NH; h++) {
    const int buf = h & 1;
    VM_WAIT0;
    WG_BARRIER;
    if (h + 1 < NH) {
      const f16* gq = Qp + (size_t)(bi + q0 * 16 + lr4) * DIM + (h + 1) * DK + kkw * 32 + lc4 * 8;
      const f16* gk = Kp + (size_t)(bj + q0 * 16 + lr4) * DIM + (h + 1) * DK + kkw * 32 + lc4 * 8;
#pragma unroll
      for (int t = 0; t < 2; t++) {
        gload_lds16(gq + (size_t)t * 16 * DIM, &Qs[buf ^ 1][kkw][(q0 + t) * 16 * 32]);
        gload_lds16(gk + (size_t)t * 16 * DIM, &Ks[buf ^ 1][kkw][(q0 + t) * 16 * 32]);
      }
    }

#pragma unroll
    for (int mi = 0; mi < 2; mi++) {
      f16x8 af0 = *(const f16x8*)&Qs[buf][0][(wm + mi * 16 + l16) * 32 + qd * 8];
      f16x8 af1 = *(const f16x8*)&Qs[buf][1][(wm + mi * 16 + l16) * 32 + qd * 8];
#pragma unroll
      for (int ni = 0; ni < 2; ni++) {
        f16x8 bf0 = *(const f16x8*)&Ks[buf][0][(wn + ni * 16 + l16) * 32 + qd * 8];
        f16x8 bf1 = *(const f16x8*)&Ks[buf][1][(wn + ni * 16 + l16) * 32 + qd * 8];
        f32x4 s = {0.f, 0.f, 0.f, 0.f};
        s = MFMA(af0, bf0, s);  // kk order identical to attn_ctx
        s = MFMA(af1, bf1, s);
#pragma unroll
        for (int r = 0; r < 4; r++) dsum[mi][ni][r] += exp_s(s[r]);
      }
    }
  }
#pragma unroll
  for (int mi = 0; mi < 2; mi++)
#pragma unroll
    for (int ni = 0; ni < 2; ni++)
#pragma unroll
      for (int r = 0; r < 4; r++) {
        const int gi = bi + wm + mi * 16 + qd * 4 + r;
        const int gj = bj + wn + ni * 16 + l16;
        IDn[(size_t)gi * S_LEN + gj] = (f16)(1.f / dsum[mi][ni][r]);
      }
}

// ---------------------------------------------------------------- pass B: ctx (R7 version)
// grid (S/128, NH, 4). Pipelined K/V LDS double-buffer + register IDn prefetch.
__global__ __launch_bounds__(256, 4) void attn_ctx(const f16* __restrict__ Qp,
                                                   const f16* __restrict__ Kp,
                                                   const f16* __restrict__ Vt,
                                                   const f16* __restrict__ IDn,
                                                   float* __restrict__ Cp) {
  __shared__ __align__(16) f16 Ks[2][2][32 * 32];  // [buf][kk][j][32]
  __shared__ __align__(16) f16 Vs[2][64 * 32];     // [buf][d][j32]
  __shared__ __align__(16) f16 Pl[4][32 * 40];     // stride 40: 2-way only
  const int tid = threadIdx.x;
  const int wv = tid >> 6;
  const int lane = tid & 63;
  const int qd = lane >> 4;
  const int l16 = lane & 15;
  const int h = blockIdx.y;
  const int i0 = blockIdx.x * 128;
  const int iw = i0 + wv * 32;
  const int jb = blockIdx.z * 512;
  const int lr4 = lane >> 2, lc4 = lane & 3;
  const int kkw = wv & 1;
  const int rhw = wv >> 1;
  f16* pl = Pl[wv];

  f16x8 aq[2][2];
#pragma unroll
  for (int mi = 0; mi < 2; mi++)
#pragma unroll
    for (int kk = 0; kk < 2; kk++)
      aq[mi][kk] = *(const f16x8*)(Qp + (size_t)(iw + mi * 16 + l16) * DIM +
                                   h * DK + kk * 32 + qd * 8);

  f32x4 acc[2][4];
#pragma unroll
  for (int a = 0; a < 2; a++)
#pragma unroll
    for (int b = 0; b < 4; b++) acc[a][b] = (f32x4){0.f, 0.f, 0.f, 0.f};

  f16x8 idn[2][2];

  {
    const int j0 = jb;
    gload_lds16(Kp + (size_t)(j0 + rhw * 16 + lr4) * DIM + h * DK + kkw * 32 + lc4 * 8,
                &Ks[0][kkw][(rhw * 16) * 32]);
    gload_lds16(Vt + (size_t)(h * DK + wv * 16 + lr4) * S_LEN + j0 + lc4 * 8,
                &Vs[0][(wv * 16) * 32]);
#pragma unroll
    for (int mi = 0; mi < 2; mi++)
      idn[0][mi] = *(const f16x8*)(IDn + (size_t)(iw + mi * 16 + l16) * S_LEN + j0 + qd * 8);
  }

#pragma unroll 2
  for (int jt = 0; jt < 16; jt++) {
    const int buf = jt & 1;
    VM_WAIT0;
    WG_BARRIER;

    if (jt + 1 < 16) {
      const int j1 = jb + (jt + 1) * 32;
      gload_lds16(Kp + (size_t)(j1 + rhw * 16 + lr4) * DIM + h * DK + kkw * 32 + lc4 * 8,
                  &Ks[buf ^ 1][kkw][(rhw * 16) * 32]);
      gload_lds16(Vt + (size_t)(h * DK + wv * 16 + lr4) * S_LEN + j1 + lc4 * 8,
                  &Vs[buf ^ 1][(wv * 16) * 32]);
#pragma unroll
      for (int mi = 0; mi < 2; mi++)
        idn[buf ^ 1][mi] =
            *(const f16x8*)(IDn + (size_t)(iw + mi * 16 + l16) * S_LEN + j1 + qd * 8);
    }

    f16x8 bk[2][2];
#pragma unroll
    for (int ni = 0; ni < 2; ni++)
#pragma unroll
      for (int kk = 0; kk < 2; kk++)
        bk[ni][kk] = *(const f16x8*)&Ks[buf][kk][(ni * 16 + l16) * 32 + qd * 8];
#pragma unroll
    for (int mi = 0; mi < 2; mi++)
#pragma unroll
      for (int ni = 0; ni < 2; ni++) {
        f32x4 s = {0.f, 0.f, 0.f, 0.f};
        s = MFMA(aq[mi][0], bk[ni][0], s);  // same order as attn_denom
        s = MFMA(aq[mi][1], bk[ni][1], s);
#pragma unroll
        for (int r = 0; r < 4; r++)
          pl[(mi * 16 + qd * 4 + r) * 40 + ni * 16 + l16] = (f16)exp_s(s[r]);
      }

    f16x8 bv[4];
#pragma unroll
    for (int nd = 0; nd < 4; nd++)
      bv[nd] = *(const f16x8*)&Vs[buf][(nd * 16 + l16) * 32 + qd * 8];
#pragma unroll
    for (int mi = 0; mi < 2; mi++) {
      f16x8 ef = *(const f16x8*)&pl[(mi * 16 + l16) * 40 + qd * 8];  // wave-private
      f16x8 p = ef * idn[buf][mi];
#pragma unroll
      for (int nd = 0; nd < 4; nd++)
        acc[mi][nd] = MFMA(p, bv[nd], acc[mi][nd]);
    }
  }

#pragma unroll
  for (int mi = 0; mi < 2; mi++)
#pragma unroll
    for (int nd = 0; nd < 4; nd++)
#pragma unroll
      for (int r = 0; r < 4; r++)
        atomicAdd(&Cp[(size_t)(iw + mi * 16 + qd * 4 + r) * DIM + h * DK + nd * 16 + l16],
                  acc[mi][nd][r]);
}

// ---------------------------------------------------------------- launcher
extern "C" void kernel_launch(void* const* d_in, const int* in_sizes, int n_in,
                              void* d_out, int out_size, void* d_ws, size_t ws_size,
                              hipStream_t stream) {
  const float* q  = (const float*)d_in[0];
  const float* k  = (const float*)d_in[1];
  const float* v  = (const float*)d_in[2];
  const float* Wq = (const float*)d_in[3];
  const float* bq = (const float*)d_in[4];
  const float* Wk = (const float*)d_in[5];
  const float* bk = (const float*)d_in[6];
  const float* Wv = (const float*)d_in[7];
  const float* bv = (const float*)d_in[8];
  const float* Wo = (const float*)d_in[9];
  const float* bo = (const float*)d_in[10];
  float* out = (float*)d_out;

  f16* w = (f16*)d_ws;
  f16* qh  = w;                          // 0..4MB
  f16* kh  = qh + (size_t)S_LEN * DIM;   // 4..8
  f16* vh  = kh + (size_t)S_LEN * DIM;   // 8..12
  f16* wqh = vh + (size_t)S_LEN * DIM;   // 12..14
  f16* wkh = wqh + (size_t)DIM * DIM;    // 14..16
  f16* wvh = wkh + (size_t)DIM * DIM;    // 16..18
  f16* woh = wvh + (size_t)DIM * DIM;    // 18..20
  f16* Qp  = woh + (size_t)DIM * DIM;    // 20..24
  f16* Kp  = Qp + (size_t)S_LEN * DIM;   // 24..28
  f16* Vt  = Kp + (size_t)S_LEN * DIM;   // 28..32
  f16* IDn = qh;                         // 0..8MB  [qh/kh dead after gemm_qkv]
  float* Cp = (float*)vh;                // 8..16MB [vh/wqh/wkh dead after gemm_qkv]

  dim3 b256(256);
  // segs 10,11 zero d_out (safe: gemm_out is the only writer of d_out, later)
  cvt_all<<<dim3(1024, 12), b256, 0, stream>>>(q, k, v, Wq, Wk, Wv, Wo,
                                               qh, kh, vh, wqh, wkh, wvh, woh, out);

  gemm_qkv<<<dim3(DIM / 64, S_LEN / 128, 3), b256, 0, stream>>>(
      qh, kh, vh, wqh, wkh, wvh, bq, bk, bv, Qp, Kp, Vt);

  // Cp aliases vh/wqh/wkh -> zero only after gemm_qkv consumed them
  hipMemsetAsync(Cp, 0, (size_t)S_LEN * DIM * sizeof(float), stream);

  attn_denom<<<dim3(S_LEN / 64, S_LEN / 64), b256, 0, stream>>>(Qp, Kp, IDn);
  attn_ctx<<<dim3(S_LEN / 128, NH, 4), b256, 0, stream>>>(Qp, Kp, Vt, IDn, Cp);

  gemm_out<<<dim3(DIM / 64, S_LEN / 128, 2), b256, 0, stream>>>(Cp, woh, bo, out);
}